// Round 3
// baseline (933.443 us; speedup 1.0000x reference)
//
#include <hip/hip_runtime.h>

#define D_IN  64
#define D_HID 16
#define D_OUT 32

// Edge-index dtype: harness doc says integer inputs arrive as const int*.
// Reference creates int64 — if output validates as garbage, flip this to 1.
#define EDGE_INDEX_IS_I64 0
#if EDGE_INDEX_IS_I64
typedef long long eidx_t;
#else
typedef int eidx_t;
#endif

// ---------------------------------------------------------------------------
// K1: weighted in-degree at targets, plus self-loop weight 1.0 per node.
//     deg[col[e]] += w[e]  for e in [0,E);  deg[i] += 1.0 for i in [0,N)
// ---------------------------------------------------------------------------
__global__ void k_degree(const eidx_t* __restrict__ ei,  // [2,E]: ei[0..E)=row, ei[E..2E)=col
                         const float* __restrict__ w,    // [E]
                         float* __restrict__ deg,        // [N], pre-zeroed
                         int E, int N) {
    int total = E + N;
    for (int i = blockIdx.x * blockDim.x + threadIdx.x; i < total;
         i += gridDim.x * blockDim.x) {
        if (i < E) {
            atomicAdd(&deg[(int)ei[(size_t)E + i]], w[i]);
        } else {
            atomicAdd(&deg[i - E], 1.0f);
        }
    }
}

// ---------------------------------------------------------------------------
// K2: hs[n][f] = (sum_k x[n][k] * Wg[k][f]) * dinv[n];  dinv[n] = rsqrt(deg[n])
//     Block = 256 threads = 16 nodes x 16 features. W_gcn staged in LDS (4KB).
// ---------------------------------------------------------------------------
__global__ void k_transform(const float* __restrict__ x,    // [N,64]
                            const float* __restrict__ Wg,   // [64,16]
                            const float* __restrict__ deg,  // [N]
                            float* __restrict__ hs,         // [N,16] out
                            float* __restrict__ dinv,       // [N] out
                            int N) {
    __shared__ float Wl[D_IN * D_HID];
    for (int i = threadIdx.x; i < D_IN * D_HID; i += blockDim.x) Wl[i] = Wg[i];
    __syncthreads();

    const int npb = 256 / D_HID;            // 16 nodes per block
    const int f  = threadIdx.x & (D_HID - 1);
    const int nl = threadIdx.x / D_HID;

    for (int n0 = blockIdx.x * npb; n0 < N; n0 += gridDim.x * npb) {
        int n = n0 + nl;
        if (n >= N) continue;
        const float* xr = x + (size_t)n * D_IN;
        float acc = 0.f;
#pragma unroll
        for (int k = 0; k < D_IN; ++k) acc += xr[k] * Wl[k * D_HID + f];
        float d  = deg[n];
        float di = d > 0.f ? rsqrtf(d) : 0.f;
        hs[(size_t)n * D_HID + f] = acc * di;
        if (f == 0) dinv[n] = di;
    }
}

// ---------------------------------------------------------------------------
// K3: edge scatter.  tmp[col[e]][f] += hs[row[e]][f] * w[e]
//     4 threads per edge, one float4 of features each (4 f32 atomics each).
//     hs/tmp are ~6.4MB each -> L2/L3 resident; streams ei + w from HBM.
// ---------------------------------------------------------------------------
__global__ void k_scatter(const eidx_t* __restrict__ ei,
                          const float* __restrict__ w,
                          const float4* __restrict__ hs4,  // [N,4] of float4
                          float* __restrict__ tmp,         // [N,16], pre-zeroed
                          int E) {
    long long total = (long long)E * 4;
    for (long long t = (long long)blockIdx.x * blockDim.x + threadIdx.x; t < total;
         t += (long long)gridDim.x * blockDim.x) {
        int e = (int)(t >> 2);
        int q = (int)(t & 3);
        int r = (int)ei[e];
        int c = (int)ei[(size_t)E + e];
        float wt = w[e];
        float4 hv = hs4[(size_t)r * 4 + q];
        float* dst = tmp + (size_t)c * D_HID + q * 4;
        atomicAdd(dst + 0, hv.x * wt);
        atomicAdd(dst + 1, hv.y * wt);
        atomicAdd(dst + 2, hv.z * wt);
        atomicAdd(dst + 3, hv.w * wt);
    }
}

// ---------------------------------------------------------------------------
// K4: out[n][o] = sum_f relu(dinv[n]*(tmp[n][f]+hs[n][f]) + bg[f]) * Wo[f][o] + bo[o]
//     (self-loop term folded analytically: dinv[c]^2 * h[c] == dinv[c] * hs[c],
//      so self-loops cost zero atomics in K3.)
//     Block = 256 threads = 8 nodes x 32 out-features. W_out + b_gcn in LDS.
// ---------------------------------------------------------------------------
__global__ void k_output(const float* __restrict__ tmp,
                         const float* __restrict__ hs,
                         const float* __restrict__ dinv,
                         const float* __restrict__ bg,   // [16]
                         const float* __restrict__ Wo,   // [16,32]
                         const float* __restrict__ bo,   // [32]
                         float* __restrict__ out,        // [N,32]
                         int N) {
    __shared__ float Wl[D_HID * D_OUT];
    __shared__ float bgl[D_HID];
    for (int i = threadIdx.x; i < D_HID * D_OUT; i += blockDim.x) Wl[i] = Wo[i];
    if (threadIdx.x < D_HID) bgl[threadIdx.x] = bg[threadIdx.x];
    __syncthreads();

    const int npb = 256 / D_OUT;            // 8 nodes per block
    const int o  = threadIdx.x & (D_OUT - 1);
    const int nl = threadIdx.x / D_OUT;

    for (int n0 = blockIdx.x * npb; n0 < N; n0 += gridDim.x * npb) {
        int n = n0 + nl;
        if (n >= N) continue;
        float di  = dinv[n];
        float acc = bo[o];
#pragma unroll
        for (int ff = 0; ff < D_HID; ++ff) {
            float e = di * (tmp[(size_t)n * D_HID + ff] + hs[(size_t)n * D_HID + ff]) + bgl[ff];
            e = fmaxf(e, 0.f);
            acc += e * Wl[ff * D_OUT + o];
        }
        out[(size_t)n * D_OUT + o] = acc;
    }
}

// ---------------------------------------------------------------------------
// Workspace layout (floats):
//   [0,16N)        tmp   (zeroed)
//   [16N,17N)      deg   (zeroed)
//   [17N,33N)      hs
//   [33N,34N)      dinv
// Total: 34N*4 bytes = 13.6 MB for N=100000.
// ---------------------------------------------------------------------------
extern "C" void kernel_launch(void* const* d_in, const int* in_sizes, int n_in,
                              void* d_out, int out_size, void* d_ws, size_t ws_size,
                              hipStream_t stream) {
    const float*  x  = (const float*)d_in[0];
    const eidx_t* ei = (const eidx_t*)d_in[1];
    const float*  ew = (const float*)d_in[2];
    const float*  Wg = (const float*)d_in[3];
    const float*  bg = (const float*)d_in[4];
    const float*  Wo = (const float*)d_in[5];
    const float*  bo = (const float*)d_in[6];
    float* out = (float*)d_out;

    const int N = in_sizes[0] / D_IN;     // 100000
    const int E = in_sizes[2];            // 3200000

    float* ws   = (float*)d_ws;
    float* tmp  = ws;                      // 16N
    float* deg  = ws + (size_t)16 * N;     // N
    float* hs   = ws + (size_t)17 * N;     // 16N
    float* dinv = ws + (size_t)33 * N;     // N

    // zero tmp + deg (harness poisons ws with 0xAA before every call)
    hipMemsetAsync(d_ws, 0, (size_t)17 * N * sizeof(float), stream);

    {   // K1: degree
        int total = E + N;
        int grid = (total + 255) / 256;
        k_degree<<<grid, 256, 0, stream>>>(ei, ew, deg, E, N);
    }
    {   // K2: transform + dinv
        int grid = (N + 15) / 16;
        k_transform<<<grid, 256, 0, stream>>>(x, Wg, deg, hs, dinv, N);
    }
    {   // K3: edge scatter
        long long total = (long long)E * 4;
        int grid = (int)((total + 255) / 256);
        k_scatter<<<grid, 256, 0, stream>>>(ei, ew, (const float4*)hs, tmp, E);
    }
    {   // K4: relu + output GEMM
        int grid = (N + 7) / 8;
        k_output<<<grid, 256, 0, stream>>>(tmp, hs, dinv, bg, Wo, bo, out, N);
    }
}

// Round 4
// 492.251 us; speedup vs baseline: 1.8963x; 1.8963x over previous
//
#include <hip/hip_runtime.h>

#define D_IN  64
#define D_HID 16
#define D_OUT 32

typedef int eidx_t;  // R3 passed with int32 — harness delivers edge_index as int32.

// ===========================================================================
// NEW CSR PATH — replaces 51.2M f32 atomics with 6.4M int atomics + gather.
// ===========================================================================

// K1: integer in-degree histogram over col.
__global__ void k_hist(const int* __restrict__ col, int* __restrict__ cnt, int E) {
    for (int i = blockIdx.x * blockDim.x + threadIdx.x; i < E;
         i += gridDim.x * blockDim.x)
        atomicAdd(&cnt[col[i]], 1);
}

// K2a: per-256-chunk exclusive scan; chunk totals to bsum.
__global__ void k_scan1(const int* __restrict__ cnt, int* __restrict__ offs,
                        int* __restrict__ bsum, int N) {
    __shared__ int s[256];
    int i = blockIdx.x * 256 + threadIdx.x;
    int v = (i < N) ? cnt[i] : 0;
    s[threadIdx.x] = v;
    __syncthreads();
    for (int off = 1; off < 256; off <<= 1) {
        int t = (threadIdx.x >= off) ? s[threadIdx.x - off] : 0;
        __syncthreads();
        s[threadIdx.x] += t;
        __syncthreads();
    }
    if (i < N) offs[i] = s[threadIdx.x] - v;        // chunk-local exclusive
    if (threadIdx.x == 255) bsum[blockIdx.x] = s[255];
}

// K2b: single-block exclusive scan of chunk totals (tiled, any nchunk).
__global__ void k_scan2(int* __restrict__ bsum, int nchunk) {
    __shared__ int s[512];
    __shared__ int basev;
    if (threadIdx.x == 0) basev = 0;
    __syncthreads();
    for (int start = 0; start < nchunk; start += 512) {
        int idx = start + threadIdx.x;
        int v = (idx < nchunk) ? bsum[idx] : 0;
        s[threadIdx.x] = v;
        __syncthreads();
        for (int off = 1; off < 512; off <<= 1) {
            int t = (threadIdx.x >= off) ? s[threadIdx.x - off] : 0;
            __syncthreads();
            s[threadIdx.x] += t;
            __syncthreads();
        }
        if (idx < nchunk) bsum[idx] = basev + s[threadIdx.x] - v;
        __syncthreads();
        if (threadIdx.x == 0) basev += s[511];
        __syncthreads();
    }
}

// K2c: add chunk bases; set offs[N]=E.
__global__ void k_scan3(int* __restrict__ offs, const int* __restrict__ bsum,
                        int N, int E) {
    int i = blockIdx.x * blockDim.x + threadIdx.x;
    if (i < N) offs[i] += bsum[i >> 8];
    if (i == 0) offs[N] = E;
}

// K3: scatter edges into CSR slots. cnt counts down to 0 (reused as cursor).
//     Packed (row, w) as int2 -> one 8B store per edge.
__global__ void k_fill(const int* __restrict__ ei, const float* __restrict__ w,
                       const int* __restrict__ offs, int* __restrict__ cnt,
                       int2* __restrict__ csr, int E) {
    for (int e = blockIdx.x * blockDim.x + threadIdx.x; e < E;
         e += gridDim.x * blockDim.x) {
        int r = ei[e];
        int c = ei[(size_t)E + e];
        float wt = w[e];
        int slot = offs[c] + atomicSub(&cnt[c], 1) - 1;
        csr[slot] = make_int2(r, __float_as_int(wt));
    }
}

// K4: dinv[n] = rsqrt(1 + sum of incoming w)  (self-loop weight 1; always > 0)
__global__ void k_deg(const int2* __restrict__ csr, const int* __restrict__ offs,
                      float* __restrict__ dinv, int N) {
    for (int n = blockIdx.x * blockDim.x + threadIdx.x; n < N;
         n += gridDim.x * blockDim.x) {
        int s = offs[n], t = offs[n + 1];
        float d = 1.0f;
        for (int i = s; i < t; ++i) d += __int_as_float(csr[i].y);
        dinv[n] = rsqrtf(d);
    }
}

// K5: hs[n][f] = (x[n] . Wg[:,f]) * dinv[n].  16 nodes/block; x tile staged in
//     LDS with pad-68 rows (conflict-free: bank = (4*nl + k) distinct per nl).
__global__ __launch_bounds__(256) void k_transform(
        const float4* __restrict__ x4,   // [N,16] float4 view of [N,64]
        const float* __restrict__ Wg,    // [64,16]
        const float* __restrict__ dinv,
        float* __restrict__ hs, int N) {
    __shared__ float Wl[D_IN * D_HID];   // 4KB
    __shared__ float xlf[16][68];        // padded x tile
    for (int i = threadIdx.x; i < D_IN * D_HID; i += 256) Wl[i] = Wg[i];
    const int f = threadIdx.x & 15, nl = threadIdx.x >> 4;
    for (int base = blockIdx.x * 16; base < N; base += gridDim.x * 16) {
        __syncthreads();                 // covers Wl (iter 0) + xlf reuse
        {
            int n = base + nl;           // thread (nl, f) loads quad f of node nl
            if (n < N) {
                float4 v = x4[(size_t)n * 16 + f];
                xlf[nl][f * 4 + 0] = v.x;
                xlf[nl][f * 4 + 1] = v.y;
                xlf[nl][f * 4 + 2] = v.z;
                xlf[nl][f * 4 + 3] = v.w;
            }
        }
        __syncthreads();
        int n = base + nl;
        if (n < N) {
            float acc = 0.f;
#pragma unroll
            for (int k = 0; k < D_IN; ++k) acc += xlf[nl][k] * Wl[k * D_HID + f];
            hs[(size_t)n * D_HID + f] = acc * dinv[n];
        }
    }
}

// K6: fused aggregate + bias + relu + output GEMM.
//     Phase1: 16 nodes x 16 f -> gather-sum over CSR segment (no atomics),
//             e = relu(dinv*(acc + hs_self) + bg) into LDS.
//     Phase2: 8 nodes x 32 o, x2 reps -> out = bo + e . Wo.
__global__ __launch_bounds__(256) void k_agg_out(
        const int2* __restrict__ csr, const int* __restrict__ offs,
        const float* __restrict__ hs, const float* __restrict__ dinv,
        const float* __restrict__ bg, const float* __restrict__ Wo,
        const float* __restrict__ bo, float* __restrict__ out, int N) {
    __shared__ float Wl[D_HID * D_OUT];  // 2KB
    __shared__ float bgl[D_HID];
    __shared__ float es[16][17];
    for (int i = threadIdx.x; i < D_HID * D_OUT; i += 256) Wl[i] = Wo[i];
    if (threadIdx.x < D_HID) bgl[threadIdx.x] = bg[threadIdx.x];
    const int f = threadIdx.x & 15, nl = threadIdx.x >> 4;
    const int o = threadIdx.x & 31, n2 = threadIdx.x >> 5;
    const float bo_r = bo[o];
    for (int base = blockIdx.x * 16; base < N; base += gridDim.x * 16) {
        __syncthreads();                 // covers Wl/bgl (iter 0) + es reuse
        int n = base + nl;
        if (n < N) {
            int s = offs[n], t = offs[n + 1];
            float acc = 0.f;
            int i = s;
            for (; i + 1 < t; i += 2) {  // 2-way ILP on the dependent gathers
                int2 v0 = csr[i], v1 = csr[i + 1];
                acc += hs[(size_t)v0.x * D_HID + f] * __int_as_float(v0.y);
                acc += hs[(size_t)v1.x * D_HID + f] * __int_as_float(v1.y);
            }
            if (i < t) {
                int2 v = csr[i];
                acc += hs[(size_t)v.x * D_HID + f] * __int_as_float(v.y);
            }
            float e = dinv[n] * (acc + hs[(size_t)n * D_HID + f]) + bgl[f];
            es[nl][f] = fmaxf(e, 0.f);
        }
        __syncthreads();
#pragma unroll
        for (int rep = 0; rep < 2; ++rep) {
            int ng = base + n2 + rep * 8;
            if (ng < N) {
                float acc = bo_r;
#pragma unroll
                for (int ff = 0; ff < D_HID; ++ff)
                    acc += es[n2 + rep * 8][ff] * Wl[ff * D_OUT + o];
                out[(size_t)ng * D_OUT + o] = acc;
            }
        }
    }
}

// ===========================================================================
// FALLBACK (proven R3 path) — used only if ws_size < CSR-path requirement.
// ===========================================================================
__global__ void k_degree(const eidx_t* __restrict__ ei, const float* __restrict__ w,
                         float* __restrict__ deg, int E, int N) {
    int total = E + N;
    for (int i = blockIdx.x * blockDim.x + threadIdx.x; i < total;
         i += gridDim.x * blockDim.x) {
        if (i < E) atomicAdd(&deg[(int)ei[(size_t)E + i]], w[i]);
        else       atomicAdd(&deg[i - E], 1.0f);
    }
}
__global__ void k_transform_old(const float* __restrict__ x, const float* __restrict__ Wg,
                                const float* __restrict__ deg, float* __restrict__ hs,
                                float* __restrict__ dinv, int N) {
    __shared__ float Wl[D_IN * D_HID];
    for (int i = threadIdx.x; i < D_IN * D_HID; i += blockDim.x) Wl[i] = Wg[i];
    __syncthreads();
    const int f = threadIdx.x & (D_HID - 1);
    const int nl = threadIdx.x / D_HID;
    for (int n0 = blockIdx.x * 16; n0 < N; n0 += gridDim.x * 16) {
        int n = n0 + nl;
        if (n >= N) continue;
        const float* xr = x + (size_t)n * D_IN;
        float acc = 0.f;
#pragma unroll
        for (int k = 0; k < D_IN; ++k) acc += xr[k] * Wl[k * D_HID + f];
        float d = deg[n];
        float di = d > 0.f ? rsqrtf(d) : 0.f;
        hs[(size_t)n * D_HID + f] = acc * di;
        if (f == 0) dinv[n] = di;
    }
}
__global__ void k_scatter(const eidx_t* __restrict__ ei, const float* __restrict__ w,
                          const float4* __restrict__ hs4, float* __restrict__ tmp, int E) {
    long long total = (long long)E * 4;
    for (long long t = (long long)blockIdx.x * blockDim.x + threadIdx.x; t < total;
         t += (long long)gridDim.x * blockDim.x) {
        int e = (int)(t >> 2);
        int q = (int)(t & 3);
        int r = (int)ei[e];
        int c = (int)ei[(size_t)E + e];
        float wt = w[e];
        float4 hv = hs4[(size_t)r * 4 + q];
        float* dst = tmp + (size_t)c * D_HID + q * 4;
        atomicAdd(dst + 0, hv.x * wt);
        atomicAdd(dst + 1, hv.y * wt);
        atomicAdd(dst + 2, hv.z * wt);
        atomicAdd(dst + 3, hv.w * wt);
    }
}
__global__ void k_output(const float* __restrict__ tmp, const float* __restrict__ hs,
                         const float* __restrict__ dinv, const float* __restrict__ bg,
                         const float* __restrict__ Wo, const float* __restrict__ bo,
                         float* __restrict__ out, int N) {
    __shared__ float Wl[D_HID * D_OUT];
    __shared__ float bgl[D_HID];
    for (int i = threadIdx.x; i < D_HID * D_OUT; i += blockDim.x) Wl[i] = Wo[i];
    if (threadIdx.x < D_HID) bgl[threadIdx.x] = bg[threadIdx.x];
    __syncthreads();
    const int o = threadIdx.x & (D_OUT - 1);
    const int nl = threadIdx.x / D_OUT;
    for (int n0 = blockIdx.x * 8; n0 < N; n0 += gridDim.x * 8) {
        int n = n0 + nl;
        if (n >= N) continue;
        float di = dinv[n];
        float acc = bo[o];
#pragma unroll
        for (int ff = 0; ff < D_HID; ++ff) {
            float e = di * (tmp[(size_t)n * D_HID + ff] + hs[(size_t)n * D_HID + ff]) + bgl[ff];
            acc += fmaxf(e, 0.f) * Wl[ff * D_OUT + o];
        }
        out[(size_t)n * D_OUT + o] = acc;
    }
}

// ===========================================================================
extern "C" void kernel_launch(void* const* d_in, const int* in_sizes, int n_in,
                              void* d_out, int out_size, void* d_ws, size_t ws_size,
                              hipStream_t stream) {
    const float*  x  = (const float*)d_in[0];
    const eidx_t* ei = (const eidx_t*)d_in[1];
    const float*  ew = (const float*)d_in[2];
    const float*  Wg = (const float*)d_in[3];
    const float*  bg = (const float*)d_in[4];
    const float*  Wo = (const float*)d_in[5];
    const float*  bo = (const float*)d_in[6];
    float* out = (float*)d_out;

    const int N = in_sizes[0] / D_IN;     // 100000
    const int E = in_sizes[2];            // 3200000
    const int nchunk = (N + 255) / 256;

    // CSR-path workspace (4B units):
    //   hs[16N] | dinv[N] | cnt[N] | offs[N+1] | bsum[nchunk] | pad | csr[2E]
    float* ws   = (float*)d_ws;
    float* hs   = ws;                                  // 16N
    float* dinv = ws + (size_t)16 * N;                 // N
    int*   cnt  = (int*)(ws + (size_t)17 * N);         // N
    int*   offs = (int*)(ws + (size_t)18 * N);         // N+1
    int*   bsum = (int*)(ws + (size_t)19 * N + 2);     // nchunk
    size_t csr_off = ((size_t)19 * N + 2 + nchunk + 1) & ~(size_t)1;  // 8B align
    int2*  csr  = (int2*)(ws + csr_off);               // E int2 = 2E
    size_t need = (csr_off + (size_t)2 * E) * sizeof(float);

    if (ws_size >= need) {
        // -------- CSR path --------
        hipMemsetAsync(cnt, 0, (size_t)N * sizeof(int), stream);
        k_hist<<<2048, 256, 0, stream>>>(ei + E, cnt, E);
        k_scan1<<<nchunk, 256, 0, stream>>>(cnt, offs, bsum, N);
        k_scan2<<<1, 512, 0, stream>>>(bsum, nchunk);
        k_scan3<<<nchunk, 256, 0, stream>>>(offs, bsum, N, E);
        k_fill<<<2048, 256, 0, stream>>>(ei, ew, offs, cnt, csr, E);
        k_deg<<<(N + 255) / 256, 256, 0, stream>>>(csr, offs, dinv, N);
        k_transform<<<(N + 15) / 16, 256, 0, stream>>>((const float4*)x, Wg, dinv, hs, N);
        k_agg_out<<<(N + 15) / 16, 256, 0, stream>>>(csr, offs, hs, dinv, bg, Wo, bo, out, N);
    } else {
        // -------- fallback: proven R3 atomic-scatter path (needs 34N floats) --------
        float* tmp  = ws;                              // 16N
        float* deg  = ws + (size_t)16 * N;             // N
        float* hs2  = ws + (size_t)17 * N;             // 16N
        float* din2 = ws + (size_t)33 * N;             // N
        hipMemsetAsync(d_ws, 0, (size_t)17 * N * sizeof(float), stream);
        k_degree<<<(E + N + 255) / 256, 256, 0, stream>>>(ei, ew, deg, E, N);
        k_transform_old<<<(N + 15) / 16, 256, 0, stream>>>(x, Wg, deg, hs2, din2, N);
        k_scatter<<<(int)(((long long)E * 4 + 255) / 256), 256, 0, stream>>>(ei, ew, (const float4*)hs2, tmp, E);
        k_output<<<(N + 7) / 8, 256, 0, stream>>>(tmp, hs2, din2, bg, Wo, bo, out, N);
    }
}